// Round 15
// baseline (112.364 us; speedup 1.0000x reference)
//
#include <hip/hip_runtime.h>
#include <hip/hip_bf16.h>
#include <math.h>

// Problem constants
#define B_ 512
#define L_ 256
#define D_ 256
#define V_ 100000
#define O_ 1000

typedef __attribute__((ext_vector_type(8))) short short8;
typedef __attribute__((ext_vector_type(4))) float f32x4;
typedef __attribute__((ext_vector_type(16))) float f32x16;

static __device__ __forceinline__ unsigned short f2bf(float f) {
    union { float f; unsigned u; } v; v.f = f;
    unsigned r = v.u + 0x7FFFu + ((v.u >> 16) & 1u);   // RNE (inputs are finite)
    return (unsigned short)(r >> 16);
}
static __device__ __forceinline__ float bf2f(unsigned short u) {
    union { unsigned u; float f; } v; v.u = ((unsigned)u) << 16;
    return v.f;
}
static __device__ __forceinline__ short8 pack8(float4 a, float4 c) {
    short8 o;
    o[0] = (short)f2bf(a.x); o[1] = (short)f2bf(a.y);
    o[2] = (short)f2bf(a.z); o[3] = (short)f2bf(a.w);
    o[4] = (short)f2bf(c.x); o[5] = (short)f2bf(c.y);
    o[6] = (short)f2bf(c.z); o[7] = (short)f2bf(c.w);
    return o;
}
// HW packed f32->bf16 (RNE), 2 values/instr (T12 recipe; no builtin on gfx950)
static __device__ __forceinline__ unsigned cvtpk(float lo, float hi) {
    unsigned r;
    asm("v_cvt_pk_bf16_f32 %0, %1, %2" : "=v"(r) : "v"(lo), "v"(hi));
    return r;
}
// fred bank-spread swizzle (valid as fsw(base)+j, j<4, base%4==0)
static __device__ __forceinline__ int fsw(int d) { return d ^ (((d >> 5) & 7) << 2); }

// ---------------- Kernel 1: W_b TRANSPOSED cast to bf16: Wbt[e][d] = bf16(Wb[d][e]) ----
__global__ __launch_bounds__(256) void k_wtT(const float* __restrict__ Wb,
                                             unsigned short* __restrict__ Wbt) {
    int i = blockIdx.x * 256 + threadIdx.x;       // 65536 (output index)
    int e = i >> 8, d = i & 255;
    Wbt[i] = f2bf(Wb[d * 256 + e]);
}

// ---------------- Kernel 2 (fused): gather + G = E*Wb*E^T rowmax + softmax + f_w ----------
// One block per batch, 512 threads (8 waves), 1 block/CU.
// IN-REGISTER PHASE HANDOFF (no Ht, no main-loop barriers):
//   Each wave owns 32 G-rows l in [32w, 32w+32).
//   1) gather own 32 E rows -> Es (swizzle: row r, 16B-chunk c at r*512 + (c*16 ^ ((r&15)<<4)))
//   2) P1 (32x32x16 MFMA): acc1[t] = Hs^T tile [e=32t..+32][own l] ; A = Wbt rows (GLOBAL,
//      L2-hot stream, 16B/lane), B = own E rows (ds_read, same-wave RAW). acc layout:
//      value(lane l32,hi; reg r) = Hs[l32][e=32t+(r&3)+8(r>>2)+4hi].
//   3) convert acc1 -> phase-2 B-frags b2[ks] IN REGISTERS: slot i of lane(l32,hi) needs
//      e=16ks+8hi+i -> reg (i&3)+4*(2(ks&1)+hi) of tile ks>>1, from lane-half (i>>2)&1.
//      4 cvt_pk + shfl_xor(32) half-swap per ks (T12 remap, derived for 32x32 layout).
//   4) ONE barrier (all Es staged), then P2: G^T[m][l] tiles: A = E[m-tile][e] (ds_read),
//      B = b2 (regs). rowmax per l = per-lane reg-max + one shfl_xor(32).
// tanh(max)=max(tanh) -> softmax over L -> f_w = a^T E (from Es; fred bank-swizzled).
__global__ __launch_bounds__(512, 2) void k_attn(const int* __restrict__ tok,
                                                 const float* __restrict__ emb,
                                                 const unsigned short* __restrict__ Wbt,
                                                 float* __restrict__ fw) {
    __shared__ __align__(16) char lds[148544];
    char* EsC = lds;                                   // 128KB: swizzled E_b
    float* red2    = (float*)(lds + 131072);           // 256 f32
    float* scratch = (float*)(lds + 132096);           // 16 f32
    float* fred    = (float*)(lds + 132160);           // 16 x 256 f32

    int b = blockIdx.x;
    int tid = threadIdx.x;
    int wid = tid >> 6, ln = tid & 63;
    int l32 = ln & 31, hi = ln >> 5;
    int r0 = wid << 5;                                 // own 32 rows base
    const int* tb = tok + (b << 8);

    // ---- 1) gather own 32 rows -> Es (capped unroll: bounded in-flight regs) ----
#pragma unroll 4
    for (int it = 0; it < 16; it++) {
        int g = it * 64 + ln;
        int row = r0 + (g >> 5), c16 = g & 31;
        const float4* src = (const float4*)(emb + ((size_t)tb[row] << 8) + (c16 << 3));
        short8 o = pack8(src[0], src[1]);
        *(short8*)(EsC + ((row << 9) | ((c16 << 4) ^ ((row & 15) << 4)))) = o;
    }

    // ---- 2) P1: Hs^T accs; A = Wbt global stream, B = own E rows from Es ----
    f32x16 acc1[8] = {};
    {
        int rr = r0 + l32;
        int rsw = (rr & 15) << 4;
#pragma unroll 2
        for (int ks = 0; ks < 16; ks++) {
            short8 b1 = *(const short8*)(EsC +
                ((rr << 9) | (((ks << 5) + (hi << 4)) ^ rsw)));
#pragma unroll
            for (int t = 0; t < 8; t++) {
                short8 a = *(const short8*)(Wbt + (((t << 5) + l32) << 8) + (ks << 4) + (hi << 3));
                acc1[t] = __builtin_amdgcn_mfma_f32_32x32x16_bf16(a, b1, acc1[t], 0, 0, 0);
            }
        }
    }

    // ---- 3) convert acc1 -> b2[16] (in-register Hs -> B-frags) ----
    short8 b2[16];
#pragma unroll
    for (int ks = 0; ks < 16; ks++) {
        int t = ks >> 1, base = (ks & 1) << 3;
        unsigned u0 = cvtpk(acc1[t][base + 0], acc1[t][base + 1]);
        unsigned u1 = cvtpk(acc1[t][base + 2], acc1[t][base + 3]);
        unsigned u2 = cvtpk(acc1[t][base + 4], acc1[t][base + 5]);
        unsigned u3 = cvtpk(acc1[t][base + 6], acc1[t][base + 7]);
        unsigned su0 = __shfl_xor(u0, 32);
        unsigned su1 = __shfl_xor(u1, 32);
        unsigned su2 = __shfl_xor(u2, 32);
        unsigned su3 = __shfl_xor(u3, 32);
        union { unsigned u[4]; short8 s; } w;
        w.u[0] = hi ? su2 : u0;    // slots 0,1
        w.u[1] = hi ? su3 : u1;    // slots 2,3
        w.u[2] = hi ? u2 : su0;    // slots 4,5
        w.u[3] = hi ? u3 : su1;    // slots 6,7
        b2[ks] = w.s;
    }

    __syncthreads();   // all Es rows staged (the ONLY pre-epilogue block barrier)

    // ---- 4) P2: G^T[m][own l] tiles; rowmax over m ----
    float rmax1 = -1e30f;
    for (int mt = 0; mt < 8; mt += 2) {
        f32x16 aA = {}, aB = {};
        int rrA = (mt << 5) + l32, rrB = rrA + 32;
        int swA = (rrA & 15) << 4, swB = (rrB & 15) << 4;
#pragma unroll
        for (int ks = 0; ks < 16; ks++) {
            int cc = (ks << 5) + (hi << 4);
            short8 xA = *(const short8*)(EsC + ((rrA << 9) | (cc ^ swA)));
            short8 xB = *(const short8*)(EsC + ((rrB << 9) | (cc ^ swB)));
            aA = __builtin_amdgcn_mfma_f32_32x32x16_bf16(xA, b2[ks], aA, 0, 0, 0);
            aB = __builtin_amdgcn_mfma_f32_32x32x16_bf16(xB, b2[ks], aB, 0, 0, 0);
        }
#pragma unroll
        for (int r = 0; r < 16; r++)
            rmax1 = fmaxf(rmax1, fmaxf(aA[r], aB[r]));
    }
    rmax1 = fmaxf(rmax1, __shfl_xor(rmax1, 32));   // combine the two m-half lane groups
    if (hi == 0) red2[r0 + l32] = rmax1;           // col l = l32 of own block
    __syncthreads();

    // ---- tanh + softmax over the 256 row-maxima ----
    float x = -1e30f;
    if (tid < 256) x = tanhf(red2[tid]);
    float mx = x;
#pragma unroll
    for (int s = 1; s < 64; s <<= 1) mx = fmaxf(mx, __shfl_xor(mx, s));
    if (ln == 0) scratch[wid] = mx;
    __syncthreads();
    float bm = scratch[0];
#pragma unroll
    for (int i = 1; i < 8; i++) bm = fmaxf(bm, scratch[i]);
    float e = (tid < 256) ? expf(x - bm) : 0.f;
    float sm = e;
#pragma unroll
    for (int s = 1; s < 64; s <<= 1) sm += __shfl_xor(sm, s);
    if (ln == 0) scratch[8 + wid] = sm;
    __syncthreads();
    float tot = 0.f;
#pragma unroll
    for (int i = 0; i < 8; i++) tot += scratch[8 + i];
    if (tid < 256) red2[tid] = e / tot;    // aq
    __syncthreads();

    // ---- f_w[d] = sum_l aq[l] * E_b[l][d]  (E from LDS, partials in fred, bank-swizzled) ----
    {
        int g = tid >> 5;                    // 0..15 -> l-range [16g, 16g+16)
        int d0 = (tid & 31) << 3;            // 8 d's per thread
        float s0[8] = {0.f, 0.f, 0.f, 0.f, 0.f, 0.f, 0.f, 0.f};
        int lbase = g << 4;
#pragma unroll
        for (int li = 0; li < 16; li++) {
            int l = lbase + li;
            float aql = red2[l];
            int byt = (l << 9) | ((d0 * 2) ^ ((l & 15) << 4));
            short8 v = *(const short8*)(EsC + byt);
#pragma unroll
            for (int jj = 0; jj < 8; jj++)
                s0[jj] += aql * bf2f((unsigned short)v[jj]);
        }
        f32x4 w0, w1;
        w0[0] = s0[0]; w0[1] = s0[1]; w0[2] = s0[2]; w0[3] = s0[3];
        w1[0] = s0[4]; w1[1] = s0[5]; w1[2] = s0[6]; w1[3] = s0[7];
        *(f32x4*)(fred + g * 256 + fsw(d0)) = w0;
        *(f32x4*)(fred + g * 256 + fsw(d0 + 4)) = w1;
    }
    __syncthreads();
    if (tid < 256) {
        float f = 0.f;
        int dw = fsw(tid);
#pragma unroll
        for (int g2 = 0; g2 < 16; g2++) f += fred[g2 * 256 + dw];
        fw[(b << 8) + tid] = f;
    }
}

// ---------------- Kernel 3: out = f_w @ lin_w^T + lin_b ----------------
// Single-stage LDS (1 barrier): BsT[k][n] transposed (float4 n-reads), As[m][k].
// Tile 32(M)x64(N), 256 blocks.
__global__ __launch_bounds__(256) void k_out(const float* __restrict__ fw,
                                             const float* __restrict__ lw,
                                             const float* __restrict__ lb,
                                             float* __restrict__ out) {
    __shared__ float BsT[256][68];   // [k][n]
    __shared__ float As[32][260];    // [m][k]
    int tid = threadIdx.x;
    int tx = tid & 15, ty = tid >> 4;
    int r0 = blockIdx.y * 32, n0 = blockIdx.x * 64;
#pragma unroll
    for (int it = 0; it < 8; it++) {
        int f4 = it * 256 + tid;
        int i = f4 >> 6, kc = (f4 & 63) << 2;
        *(float4*)&As[i][kc] = *(const float4*)&fw[(r0 + i) * 256 + kc];
    }
#pragma unroll
    for (int it = 0; it < 16; it++) {
        int f4 = it * 256 + tid;
        int n = f4 >> 6, kc = (f4 & 63) << 2;
        int nn = n0 + n;
        float4 v = {0.f, 0.f, 0.f, 0.f};
        if (nn < O_) v = *(const float4*)&lw[(size_t)nn * 256 + kc];
        BsT[kc][n] = v.x; BsT[kc + 1][n] = v.y; BsT[kc + 2][n] = v.z; BsT[kc + 3][n] = v.w;
    }
    __syncthreads();
    float acc[2][4] = {};
#pragma unroll 4
    for (int k = 0; k < 256; k++) {
        float4 bv = *(const float4*)&BsT[k][tx * 4];
        float a0 = As[ty * 2][k], a1 = As[ty * 2 + 1][k];
        acc[0][0] += a0 * bv.x; acc[0][1] += a0 * bv.y; acc[0][2] += a0 * bv.z; acc[0][3] += a0 * bv.w;
        acc[1][0] += a1 * bv.x; acc[1][1] += a1 * bv.y; acc[1][2] += a1 * bv.z; acc[1][3] += a1 * bv.w;
    }
#pragma unroll
    for (int i = 0; i < 2; i++)
#pragma unroll
        for (int j = 0; j < 4; j++) {
            int n = n0 + tx * 4 + j;
            if (n < O_) out[(size_t)(r0 + ty * 2 + i) * O_ + n] = acc[i][j] + lb[n];
        }
}

extern "C" void kernel_launch(void* const* d_in, const int* in_sizes, int n_in,
                              void* d_out, int out_size, void* d_ws, size_t ws_size,
                              hipStream_t stream) {
    const int* tok = (const int*)d_in[0];
    const float* emb = (const float*)d_in[1];
    const float* Wb = (const float*)d_in[2];
    const float* lw = (const float*)d_in[3];
    const float* lb = (const float*)d_in[4];
    float* out = (float*)d_out;

    char* ws = (char*)d_ws;
    unsigned short* Wbt = (unsigned short*)(ws);            // 131,072 B (transposed Wb, bf16)
    float*          fwp = (float*)(ws + 131072);            // 524,288 B

    hipLaunchKernelGGL(k_wtT,  dim3(256),    dim3(256), 0, stream, Wb, Wbt);
    hipLaunchKernelGGL(k_attn, dim3(512),    dim3(512), 0, stream, tok, emb, Wbt, fwp);
    hipLaunchKernelGGL(k_out,  dim3(16, 16), dim3(256), 0, stream, fwp, lw, lb, out);
}

// Round 16
// 72.636 us; speedup vs baseline: 1.5469x; 1.5469x over previous
//
#include <hip/hip_runtime.h>
#include <hip/hip_bf16.h>
#include <math.h>

// Problem constants
#define B_ 512
#define L_ 256
#define D_ 256
#define V_ 100000
#define O_ 1000

typedef __attribute__((ext_vector_type(8))) short short8;
typedef __attribute__((ext_vector_type(4))) float f32x4;

static __device__ __forceinline__ unsigned short f2bf(float f) {
    union { float f; unsigned u; } v; v.f = f;
    unsigned r = v.u + 0x7FFFu + ((v.u >> 16) & 1u);   // RNE (inputs are finite)
    return (unsigned short)(r >> 16);
}
static __device__ __forceinline__ float bf2f(unsigned short u) {
    union { unsigned u; float f; } v; v.u = ((unsigned)u) << 16;
    return v.f;
}
static __device__ __forceinline__ short8 pack8(float4 a, float4 c) {
    short8 o;
    o[0] = (short)f2bf(a.x); o[1] = (short)f2bf(a.y);
    o[2] = (short)f2bf(a.z); o[3] = (short)f2bf(a.w);
    o[4] = (short)f2bf(c.x); o[5] = (short)f2bf(c.y);
    o[6] = (short)f2bf(c.z); o[7] = (short)f2bf(c.w);
    return o;
}
// fred bank-spread swizzle (valid as fsw(base)+j, j<4, base%4==0)
static __device__ __forceinline__ int fsw(int d) { return d ^ (((d >> 5) & 7) << 2); }

// ---------------- Kernel 1: W_b cast to bf16 (row-major) ----------------
__global__ __launch_bounds__(256) void k_wt(const float* __restrict__ Wb,
                                            unsigned short* __restrict__ Wbf) {
    int i = blockIdx.x * 256 + threadIdx.x;       // 65536
    Wbf[i] = f2bf(Wb[i]);
}

// ---------------- Kernel 2 (fused): per-batch gather + G = E_b*W_b*E_b^T + softmax + f_w ----
// One block per batch, 512 threads (8 waves), 1 block/CU (160KB LDS).
// == r9 structure (proven 66us) with the r15-validated 4-bit swizzle ==
// Es/Ht swizzle: row r, 16B-aligned byte col c at (r<<9) | (c ^ ((r&15)<<4)).
// r9's (r&7) left rows r, r+8 aliased -> 5.0M conflict cycles; (r&15) measured 0 (r15).
// Core: full E_b in LDS (128KB), wfr regs (32 Wb rows/wave), efr regs (32 E rows/wave),
// mt-loop {P1 -> Ht 32KB; barrier; P2 rowmax; barrier}; split gather overlap (r9);
// setprio around MFMA clusters; fred store bank-swizzled.
// tanh(max)=max(tanh) -> softmax over L -> f_w = a^T E (from Es).
__global__ __launch_bounds__(512, 2) void k_attn(const int* __restrict__ tok,
                                                 const float* __restrict__ emb,
                                                 const unsigned short* __restrict__ Wbf,
                                                 float* __restrict__ fw) {
    __shared__ __align__(16) char lds[163840];
    char* EsC = lds;                                   // 128KB: swizzled E_b
    char* HtC = lds + 131072;                          // 32KB: Ht tile (64 rows x 512B, swizzled)
    float* red2    = (float*)(lds + 131072);           // overlay: 256 f32
    float* scratch = (float*)(lds + 132096);           // overlay: 16 f32
    float* fred    = (float*)(lds + 132160);           // overlay: 16 x 256 f32

    int b = blockIdx.x;
    int tid = threadIdx.x;
    int wid = tid >> 6, ln = tid & 63;
    int l16 = ln & 15, gp = ln >> 4;
    int i0 = wid * 32;          // wave's Wb-row block (P1) / G-row block (P2)
    const int* tb = tok + (b << 8);

    // ---- Wb A-frag preload (global, L2-hot): rows [i0, i0+32) -> 64 VGPR ----
    short8 wfr[8][2];
#pragma unroll
    for (int k = 0; k < 8; k++)
#pragma unroll
        for (int rf = 0; rf < 2; rf++)
            wfr[k][rf] = *(const short8*)(Wbf + ((i0 + rf * 16 + l16) << 8) + k * 32 + gp * 8);

    // ---- gather chunk 0 (rows 0..63): it 0..3 ----
#pragma unroll
    for (int it = 0; it < 4; it++) {
        int c = it * 512 + tid;
        int row = c >> 5, c16 = c & 31;
        const float4* src = (const float4*)(emb + ((size_t)tb[row] << 8) + (c16 << 3));
        short8 o = pack8(src[0], src[1]);
        *(short8*)(EsC + ((row << 9) | ((c16 << 4) ^ ((row & 15) << 4)))) = o;
    }
    __syncthreads();   // barrier A: rows 0-63 visible

    // ---- issue loads for rows 64..159 (it 4..9) into regs; land them AFTER P1(0) ----
    float4 ga[6], gb[6];
#pragma unroll
    for (int it = 0; it < 6; it++) {
        int c = (it + 4) * 512 + tid;
        int row = c >> 5, c16 = c & 31;
        const float4* src = (const float4*)(emb + ((size_t)tb[row] << 8) + (c16 << 3));
        ga[it] = src[0]; gb[it] = src[1];
    }

    float rmax[8];
#pragma unroll
    for (int i = 0; i < 8; i++) rmax[i] = -1e30f;

    // ---- phase 1 / phase 2 bodies ----
    auto P1 = [&](int m0) {
        f32x4 acc[2][4] = {};
#pragma unroll
        for (int k0 = 0; k0 < 256; k0 += 32) {
            int kk2 = (k0 + gp * 8) * 2;
            short8 bfr[4];
#pragma unroll
            for (int cf = 0; cf < 4; cf++) {
                int jg = m0 + cf * 16 + l16;
                bfr[cf] = *(const short8*)(EsC + ((jg << 9) | (kk2 ^ ((jg & 15) << 4))));
            }
            int ks = k0 >> 5;
            __builtin_amdgcn_s_setprio(1);
#pragma unroll
            for (int rf = 0; rf < 2; rf++)
#pragma unroll
                for (int cf = 0; cf < 4; cf++)
                    acc[rf][cf] = __builtin_amdgcn_mfma_f32_16x16x32_bf16(
                        wfr[ks][rf], bfr[cf], acc[rf][cf], 0, 0, 0);
            __builtin_amdgcn_s_setprio(0);
        }
        // store transposed: H'[i][j] -> Ht[j-m0][i], 8B packs, swizzled
#pragma unroll
        for (int rf = 0; rf < 2; rf++)
#pragma unroll
            for (int cf = 0; cf < 4; cf++) {
                int i = i0 + rf * 16 + gp * 4;
                int jl = cf * 16 + l16;
                unsigned long long pk;
                unsigned short* p = (unsigned short*)&pk;
                p[0] = f2bf(acc[rf][cf][0]);
                p[1] = f2bf(acc[rf][cf][1]);
                p[2] = f2bf(acc[rf][cf][2]);
                p[3] = f2bf(acc[rf][cf][3]);
                *(unsigned long long*)(HtC + ((jl << 9) | ((i * 2) ^ ((jl & 15) << 4)))) = pk;
            }
    };

    short8 efr[8][2];
    auto P2 = [&]() {
        f32x4 acc[2][4] = {};
#pragma unroll
        for (int k0 = 0; k0 < 256; k0 += 32) {
            int kk2 = (k0 + gp * 8) * 2;
            short8 bb[4];
#pragma unroll
            for (int cf = 0; cf < 4; cf++) {
                int m = cf * 16 + l16;
                bb[cf] = *(const short8*)(HtC + ((m << 9) | (kk2 ^ ((m & 15) << 4))));
            }
            int ks = k0 >> 5;
            __builtin_amdgcn_s_setprio(1);
#pragma unroll
            for (int rf = 0; rf < 2; rf++)
#pragma unroll
                for (int cf = 0; cf < 4; cf++)
                    acc[rf][cf] = __builtin_amdgcn_mfma_f32_16x16x32_bf16(
                        efr[ks][rf], bb[cf], acc[rf][cf], 0, 0, 0);
            __builtin_amdgcn_s_setprio(0);
        }
#pragma unroll
        for (int rf = 0; rf < 2; rf++)
#pragma unroll
            for (int r = 0; r < 4; r++) {
                float mx = fmaxf(fmaxf(acc[rf][0][r], acc[rf][1][r]),
                                 fmaxf(acc[rf][2][r], acc[rf][3][r]));
                rmax[rf * 4 + r] = fmaxf(rmax[rf * 4 + r], mx);
            }
    };

    // ---- P1(0) runs while rows 64-159 are in flight ----
    P1(0);

    // land rows 64..159 (disjoint from rows 0-63 P1 reads; no barrier needed)
#pragma unroll
    for (int it = 0; it < 6; it++) {
        int c = (it + 4) * 512 + tid;
        int row = c >> 5, c16 = c & 31;
        short8 o = pack8(ga[it], gb[it]);
        *(short8*)(EsC + ((row << 9) | ((c16 << 4) ^ ((row & 15) << 4)))) = o;
    }
    // gather rows 160..255 (it 10..15)
#pragma unroll
    for (int it = 10; it < 16; it++) {
        int c = it * 512 + tid;
        int row = c >> 5, c16 = c & 31;
        const float4* src = (const float4*)(emb + ((size_t)tb[row] << 8) + (c16 << 3));
        short8 o = pack8(src[0], src[1]);
        *(short8*)(EsC + ((row << 9) | ((c16 << 4) ^ ((row & 15) << 4)))) = o;
    }
    __syncthreads();   // barrier B: all E rows + Ht(0) visible

    // ---- E A-frag preload (from LDS): rows [i0, i0+32) -> 64 VGPR ----
#pragma unroll
    for (int k = 0; k < 8; k++)
#pragma unroll
        for (int rf = 0; rf < 2; rf++) {
            int l = i0 + rf * 16 + l16;
            efr[k][rf] = *(const short8*)(EsC + ((l << 9) | ((k * 64 + gp * 16) ^ ((l & 15) << 4))));
        }

    P2();              // mt = 0
    __syncthreads();

    for (int mt = 1; mt < 4; mt++) {
        P1(mt * 64);
        __syncthreads();
        P2();
        __syncthreads();
    }

    // ---- reduce rowmax across l16 lanes, publish to red2 ----
#pragma unroll
    for (int i = 0; i < 8; i++) {
        float v = rmax[i];
        v = fmaxf(v, __shfl_xor(v, 1));
        v = fmaxf(v, __shfl_xor(v, 2));
        v = fmaxf(v, __shfl_xor(v, 4));
        v = fmaxf(v, __shfl_xor(v, 8));
        rmax[i] = v;
    }
    if (l16 == 0) {
#pragma unroll
        for (int rf = 0; rf < 2; rf++)
#pragma unroll
            for (int r = 0; r < 4; r++)
                red2[i0 + rf * 16 + gp * 4 + r] = rmax[rf * 4 + r];
    }
    __syncthreads();

    // ---- tanh + softmax over the 256 row-maxima ----
    float x = -1e30f;
    if (tid < 256) x = tanhf(red2[tid]);
    float mx = x;
#pragma unroll
    for (int s = 1; s < 64; s <<= 1) mx = fmaxf(mx, __shfl_xor(mx, s));
    if (ln == 0) scratch[wid] = mx;
    __syncthreads();
    float bm = scratch[0];
#pragma unroll
    for (int i = 1; i < 8; i++) bm = fmaxf(bm, scratch[i]);
    float e = (tid < 256) ? expf(x - bm) : 0.f;
    float sm = e;
#pragma unroll
    for (int s = 1; s < 64; s <<= 1) sm += __shfl_xor(sm, s);
    if (ln == 0) scratch[8 + wid] = sm;
    __syncthreads();
    float tot = 0.f;
#pragma unroll
    for (int i = 0; i < 8; i++) tot += scratch[8 + i];
    if (tid < 256) red2[tid] = e / tot;    // aq
    __syncthreads();

    // ---- f_w[d] = sum_l aq[l] * E_b[l][d]  (E from LDS, partials in fred, bank-swizzled) ----
    {
        int g = tid >> 5;                    // 0..15 -> l-range [16g, 16g+16)
        int d0 = (tid & 31) << 3;            // 8 d's per thread
        float s0[8] = {0.f, 0.f, 0.f, 0.f, 0.f, 0.f, 0.f, 0.f};
        int lbase = g << 4;
#pragma unroll
        for (int li = 0; li < 16; li++) {
            int l = lbase + li;
            float aql = red2[l];
            int byt = (l << 9) | ((d0 * 2) ^ ((l & 15) << 4));
            short8 v = *(const short8*)(EsC + byt);
#pragma unroll
            for (int jj = 0; jj < 8; jj++)
                s0[jj] += aql * bf2f((unsigned short)v[jj]);
        }
        f32x4 w0, w1;
        w0[0] = s0[0]; w0[1] = s0[1]; w0[2] = s0[2]; w0[3] = s0[3];
        w1[0] = s0[4]; w1[1] = s0[5]; w1[2] = s0[6]; w1[3] = s0[7];
        *(f32x4*)(fred + g * 256 + fsw(d0)) = w0;
        *(f32x4*)(fred + g * 256 + fsw(d0 + 4)) = w1;
    }
    __syncthreads();
    if (tid < 256) {
        float f = 0.f;
        int dw = fsw(tid);
#pragma unroll
        for (int g2 = 0; g2 < 16; g2++) f += fred[g2 * 256 + dw];
        fw[(b << 8) + tid] = f;
    }
}

// ---------------- Kernel 3: out = f_w @ lin_w^T + lin_b ----------------
// Single-stage LDS (1 barrier): BsT[k][n] transposed (float4 n-reads), As[m][k].
// Tile 32(M)x64(N), 256 blocks.  (r14/r15-proven: ~1us)
__global__ __launch_bounds__(256) void k_out(const float* __restrict__ fw,
                                             const float* __restrict__ lw,
                                             const float* __restrict__ lb,
                                             float* __restrict__ out) {
    __shared__ float BsT[256][68];   // [k][n]
    __shared__ float As[32][260];    // [m][k]
    int tid = threadIdx.x;
    int tx = tid & 15, ty = tid >> 4;
    int r0 = blockIdx.y * 32, n0 = blockIdx.x * 64;
#pragma unroll
    for (int it = 0; it < 8; it++) {
        int f4 = it * 256 + tid;
        int i = f4 >> 6, kc = (f4 & 63) << 2;
        *(float4*)&As[i][kc] = *(const float4*)&fw[(r0 + i) * 256 + kc];
    }
#pragma unroll
    for (int it = 0; it < 16; it++) {
        int f4 = it * 256 + tid;
        int n = f4 >> 6, kc = (f4 & 63) << 2;
        int nn = n0 + n;
        float4 v = {0.f, 0.f, 0.f, 0.f};
        if (nn < O_) v = *(const float4*)&lw[(size_t)nn * 256 + kc];
        BsT[kc][n] = v.x; BsT[kc + 1][n] = v.y; BsT[kc + 2][n] = v.z; BsT[kc + 3][n] = v.w;
    }
    __syncthreads();
    float acc[2][4] = {};
#pragma unroll 4
    for (int k = 0; k < 256; k++) {
        float4 bv = *(const float4*)&BsT[k][tx * 4];
        float a0 = As[ty * 2][k], a1 = As[ty * 2 + 1][k];
        acc[0][0] += a0 * bv.x; acc[0][1] += a0 * bv.y; acc[0][2] += a0 * bv.z; acc[0][3] += a0 * bv.w;
        acc[1][0] += a1 * bv.x; acc[1][1] += a1 * bv.y; acc[1][2] += a1 * bv.z; acc[1][3] += a1 * bv.w;
    }
#pragma unroll
    for (int i = 0; i < 2; i++)
#pragma unroll
        for (int j = 0; j < 4; j++) {
            int n = n0 + tx * 4 + j;
            if (n < O_) out[(size_t)(r0 + ty * 2 + i) * O_ + n] = acc[i][j] + lb[n];
        }
}

extern "C" void kernel_launch(void* const* d_in, const int* in_sizes, int n_in,
                              void* d_out, int out_size, void* d_ws, size_t ws_size,
                              hipStream_t stream) {
    const int* tok = (const int*)d_in[0];
    const float* emb = (const float*)d_in[1];
    const float* Wb = (const float*)d_in[2];
    const float* lw = (const float*)d_in[3];
    const float* lb = (const float*)d_in[4];
    float* out = (float*)d_out;

    char* ws = (char*)d_ws;
    unsigned short* Wbf = (unsigned short*)(ws);            // 131,072 B
    float*          fwp = (float*)(ws + 131072);            // 524,288 B

    hipLaunchKernelGGL(k_wt,   dim3(256),    dim3(256), 0, stream, Wb, Wbf);
    hipLaunchKernelGGL(k_attn, dim3(512),    dim3(512), 0, stream, tok, emb, Wbf, fwp);
    hipLaunchKernelGGL(k_out,  dim3(16, 16), dim3(256), 0, stream, fwp, lw, lb, out);
}